// Round 5
// baseline (2588.928 us; speedup 1.0000x reference)
//
#include <hip/hip_runtime.h>
#include <hip/hip_bf16.h>

// ---------------------------------------------------------------------------
// y = relu((x - pb) @ W + be); thr = 128th largest per row; out = y*(y>=thr).
// M=16384, K=4096, N=4096, fp32 in/out.
//
// R8b: identical to R8 (round-4 bench was an infra failure, not a kernel
// verdict; schedule ledger re-audited — no hang/fault mode found).
// GEMM: 128x128 tile / 4 waves / 64KB LDS -> TWO blocks per CU, so one
// block's read/barrier sections overlap the other's MFMA (m114 mechanism).
// Keeps: interleaved hi|lo 128B LDS rows + 3-bit XOR swizzle (0 conflicts,
// proven R5/R7), pre-swizzled global_load_lds source, counted vmcnt
// (8 loads issued at ph0; waits vmcnt(8)/vmcnt(2); never 0 in-loop),
// setprio around MFMA, n-major bijective XCD swizzle, sched_barrier fences.
// 2 barriers per K-tile. Top-k: R7 register bisection + f64 band (proven).
// ---------------------------------------------------------------------------

typedef __bf16  bf16x8 __attribute__((ext_vector_type(8)));
typedef float   f32x4  __attribute__((ext_vector_type(4)));

__device__ __forceinline__ unsigned short f2bf(float f) {
    __hip_bfloat16 h = __float2bfloat16(f);
    return __builtin_bit_cast(unsigned short, h);
}
__device__ __forceinline__ float bf2f(unsigned short u) {
    __hip_bfloat16 h = __builtin_bit_cast(__hip_bfloat16, u);
    return __bfloat162float(h);
}

#define GLL16(g, l)                                                          \
    __builtin_amdgcn_global_load_lds(                                        \
        (const __attribute__((address_space(1))) unsigned int*)(g),          \
        (__attribute__((address_space(3))) unsigned int*)(l), 16, 0, 0)

// ---------------------------------------------------------------------------
// x [m][k] fp32 -> Xhi/Xlo [m][k] bf16 (pb folded in). One row per block.
// ---------------------------------------------------------------------------
__global__ __launch_bounds__(256)
void presplit_x(const float* __restrict__ x, const float* __restrict__ pb,
                unsigned short* __restrict__ Xhi, unsigned short* __restrict__ Xlo,
                int Kdim) {
    const size_t rbase = (size_t)blockIdx.x * Kdim;
    for (int it = 0; it < Kdim; it += 2048) {
        const int k8 = it + threadIdx.x * 8;
        __align__(16) unsigned short hi[8], lo[8];
        #pragma unroll
        for (int q = 0; q < 2; ++q) {
            float4 xv = *(const float4*)&x[rbase + k8 + q * 4];
            float4 pv = *(const float4*)&pb[k8 + q * 4];
            float v[4] = {xv.x - pv.x, xv.y - pv.y, xv.z - pv.z, xv.w - pv.w};
            #pragma unroll
            for (int r = 0; r < 4; ++r) {
                hi[q*4+r] = f2bf(v[r]);
                lo[q*4+r] = f2bf(v[r] - bf2f(hi[q*4+r]));
            }
        }
        *(uint4*)&Xhi[rbase + k8] = *(uint4*)&hi[0];
        *(uint4*)&Xlo[rbase + k8] = *(uint4*)&lo[0];
    }
}

// ---------------------------------------------------------------------------
// W [k][n] fp32 -> Wt_hi/Wt_lo [n][k] bf16 (transpose + split).
// ---------------------------------------------------------------------------
__global__ __launch_bounds__(256)
void split_transpose_W(const float* __restrict__ W,
                       unsigned short* __restrict__ Wt_hi,
                       unsigned short* __restrict__ Wt_lo,
                       int N, int Kdim) {
    __shared__ float tile[64][65];
    const int tx = threadIdx.x;
    const int nB = blockIdx.x * 64;
    const int kB = blockIdx.y * 64;

    #pragma unroll
    for (int p = 0; p < 4; ++p) {
        int e  = tx + 256 * p;
        int kl = e >> 4;
        int n4 = (e & 15) << 2;
        float4 v = *(const float4*)&W[(size_t)(kB + kl) * N + nB + n4];
        tile[kl][n4 + 0] = v.x; tile[kl][n4 + 1] = v.y;
        tile[kl][n4 + 2] = v.z; tile[kl][n4 + 3] = v.w;
    }
    __syncthreads();

    #pragma unroll
    for (int p = 0; p < 4; ++p) {
        int e  = tx + 256 * p;
        int nl = e >> 4;
        int k4 = (e & 15) << 2;
        unsigned short hi[4], lo[4];
        #pragma unroll
        for (int r = 0; r < 4; ++r) {
            float f = tile[k4 + r][nl];
            hi[r] = f2bf(f);
            lo[r] = f2bf(f - bf2f(hi[r]));
        }
        size_t off = (size_t)(nB + nl) * Kdim + kB + k4;
        *(ushort4*)&Wt_hi[off] = *(ushort4*)&hi[0];
        *(ushort4*)&Wt_lo[off] = *(ushort4*)&lo[0];
    }
}

// ---------------------------------------------------------------------------
// 128x128 tile, BK=32, 4 waves (2Mx2N), 64KB LDS -> 2 blocks/CU.
// LDS rows 128B = [hi c0..3 | lo c0..3], phys chunk = logical ^ (row&7).
// Per K-tile: 2 phases x 24 MFMA; all 8 staging GLLs issued at ph0.
// Waits: end-ph0 vmcnt(8) (publishes a2,a3 of t); end-ph1 vmcnt(2)
// (publishes B,a0,a1 of t+1). Every load gets >=2 phases of flight.
// ---------------------------------------------------------------------------
__global__ __launch_bounds__(256, 2)
void gemm_presplit_2b(const unsigned short* __restrict__ Xhi,
                      const unsigned short* __restrict__ Xlo,
                      const unsigned short* __restrict__ Wt_hi,
                      const unsigned short* __restrict__ Wt_lo,
                      const float* __restrict__ be,
                      float* __restrict__ out, int M, int N, int Kdim) {
    __shared__ unsigned short sA[2][128 * 64];   // 128 rows x 128B
    __shared__ unsigned short sB[2][128 * 64];

    const int tx   = threadIdx.x;
    const int lane = tx & 63;
    const int wv   = tx >> 6;          // 0..3
    const int ln   = lane & 15;
    const int quad = lane >> 4;
    const int wm   = wv >> 1;          // 0..1 (M half)
    const int wn   = wv & 1;           // 0..1 (N half)

    // n-major bijective XCD swizzle: A panel (2MB) L2-resident per XCD.
    const int mT = M >> 7, nT = N >> 7, total = mT * nT;
    int wgid = blockIdx.y * gridDim.x + blockIdx.x;
    int xcd = wgid & 7, idx = wgid >> 3;
    int qq = total >> 3, rr_ = total & 7;
    int swz = (xcd < rr_ ? xcd * (qq + 1) : rr_ * (qq + 1) + (xcd - rr_) * qq) + idx;
    const int mBase = (swz / nT) << 7;
    const int nBase = (swz % nT) << 7;

    // staging: 256 thr x 16B = 4KB round = 32 rows x 128B
    const int rr  = tx >> 3;           // 0..31 row-within-round
    const int lc8 = tx & 7;            // dest (physical) 16B chunk, linear
    const int lgc = lc8 ^ (rr & 7);    // logical chunk at this dest slot
    const unsigned short* aSrc = (lgc & 4) ? Xlo : Xhi;
    const unsigned short* bSrc = (lgc & 4) ? Wt_lo : Wt_hi;
    const int srcoff = (lgc & 3) << 3;

    // fragment read: logical chunk quad (hi) / 4+quad (lo); phys = ^(row&7)
    const int pA = (quad ^ (ln & 7)) << 3;       // hi; lo at pA^32

#define STAGE_B(bufp, r, k0_) do {                                            \
        int row_ = ((r) << 5) + rr;                                           \
        GLL16(bSrc + (size_t)(nBase + row_) * Kdim + (k0_) + srcoff,          \
              &sB[bufp][(row_ << 6) + (lc8 << 3)]);                           \
    } while (0)
#define STAGE_A(bufp, rbase, k0_) do {                                        \
        int row_ = (rbase) + rr;                                              \
        GLL16(aSrc + (size_t)(mBase + row_) * Kdim + (k0_) + srcoff,          \
              &sA[bufp][(row_ << 6) + (lc8 << 3)]);                           \
    } while (0)

    f32x4 acc[4][4] = {};

    const int NT = Kdim >> 5;          // K-tiles (BK=32)

    // prologue: tile 0 into buf 0 (order: B r0..3, A {0,64,32,96})
    STAGE_B(0, 0, 0); STAGE_B(0, 1, 0); STAGE_B(0, 2, 0); STAGE_B(0, 3, 0);
    STAGE_A(0, 0, 0); STAGE_A(0, 64, 0); STAGE_A(0, 32, 0); STAGE_A(0, 96, 0);
    asm volatile("s_waitcnt vmcnt(0)" ::: "memory");
    __builtin_amdgcn_s_barrier();
    __builtin_amdgcn_sched_barrier(0);

    for (int t = 0; t < NT; ++t) {
        const int cur = t & 1, nxt = cur ^ 1;
        const bool more = (t + 1 < NT);
        const int k1 = (t + 1) << 5;

        // ---------------- phase 0: stage(t+1) + B,A01 frags + 24 MFMA ------
        if (more) {    // issue order matters for FIFO vmcnt: B0..3, a0,a1,a2,a3
            STAGE_B(nxt, 0, k1); STAGE_B(nxt, 1, k1);
            STAGE_B(nxt, 2, k1); STAGE_B(nxt, 3, k1);
            STAGE_A(nxt, 0, k1); STAGE_A(nxt, 64, k1);
            STAGE_A(nxt, 32, k1); STAGE_A(nxt, 96, k1);
        }
        bf16x8 bhi[4], blo[4];         // held through both phases
        #pragma unroll
        for (int j = 0; j < 4; ++j) {
            int rb = wn * 64 + j * 16 + ln;
            bhi[j] = *(const bf16x8*)&sB[cur][(rb << 6) + pA];
            blo[j] = *(const bf16x8*)&sB[cur][(rb << 6) + (pA ^ 32)];
        }
        {
            bf16x8 ahi[2], alo[2];     // mtiles 0,1: rows wm*64 + {0..31}
            #pragma unroll
            for (int ii = 0; ii < 2; ++ii) {
                int ra = wm * 64 + ii * 16 + ln;
                ahi[ii] = *(const bf16x8*)&sA[cur][(ra << 6) + pA];
                alo[ii] = *(const bf16x8*)&sA[cur][(ra << 6) + (pA ^ 32)];
            }
            __builtin_amdgcn_s_setprio(1);
            #pragma unroll
            for (int ii = 0; ii < 2; ++ii)
                #pragma unroll
                for (int j = 0; j < 4; ++j)
                    acc[ii][j] = __builtin_amdgcn_mfma_f32_16x16x32_bf16(
                        ahi[ii], bhi[j], acc[ii][j], 0, 0, 0);
            #pragma unroll
            for (int ii = 0; ii < 2; ++ii)
                #pragma unroll
                for (int j = 0; j < 4; ++j)
                    acc[ii][j] = __builtin_amdgcn_mfma_f32_16x16x32_bf16(
                        ahi[ii], blo[j], acc[ii][j], 0, 0, 0);
            #pragma unroll
            for (int ii = 0; ii < 2; ++ii)
                #pragma unroll
                for (int j = 0; j < 4; ++j)
                    acc[ii][j] = __builtin_amdgcn_mfma_f32_16x16x32_bf16(
                        alo[ii], bhi[j], acc[ii][j], 0, 0, 0);
            __builtin_amdgcn_s_setprio(0);
        }
        // publish a2,a3(t) (oldest 2 of the 10 outstanding) before ph1 reads
        if (more) asm volatile("s_waitcnt vmcnt(8)" ::: "memory");
        else      asm volatile("s_waitcnt vmcnt(0)" ::: "memory");
        __builtin_amdgcn_s_barrier();
        __builtin_amdgcn_sched_barrier(0);

        // ---------------- phase 1: A23 frags + 24 MFMA ---------------------
        {
            bf16x8 ahi[2], alo[2];     // mtiles 2,3: rows wm*64 + {32..63}
            #pragma unroll
            for (int ii = 0; ii < 2; ++ii) {
                int ra = wm * 64 + (2 + ii) * 16 + ln;
                ahi[ii] = *(const bf16x8*)&sA[cur][(ra << 6) + pA];
                alo[ii] = *(const bf16x8*)&sA[cur][(ra << 6) + (pA ^ 32)];
            }
            __builtin_amdgcn_s_setprio(1);
            #pragma unroll
            for (int ii = 0; ii < 2; ++ii)
                #pragma unroll
                for (int j = 0; j < 4; ++j)
                    acc[2 + ii][j] = __builtin_amdgcn_mfma_f32_16x16x32_bf16(
                        ahi[ii], bhi[j], acc[2 + ii][j], 0, 0, 0);
            #pragma unroll
            for (int ii = 0; ii < 2; ++ii)
                #pragma unroll
                for (int j = 0; j < 4; ++j)
                    acc[2 + ii][j] = __builtin_amdgcn_mfma_f32_16x16x32_bf16(
                        ahi[ii], blo[j], acc[2 + ii][j], 0, 0, 0);
            #pragma unroll
            for (int ii = 0; ii < 2; ++ii)
                #pragma unroll
                for (int j = 0; j < 4; ++j)
                    acc[2 + ii][j] = __builtin_amdgcn_mfma_f32_16x16x32_bf16(
                        alo[ii], bhi[j], acc[2 + ii][j], 0, 0, 0);
            __builtin_amdgcn_s_setprio(0);
        }
        // publish B,a0,a1(t+1); leaves a2,a3(t+1) in flight (never 0 in-loop)
        asm volatile("s_waitcnt vmcnt(2)" ::: "memory");
        __builtin_amdgcn_s_barrier();
        __builtin_amdgcn_sched_barrier(0);
    }

    // epilogue: + b_enc, relu, store (C/D: col=lane&15, row=quad*4+reg)
    #pragma unroll
    for (int j = 0; j < 4; ++j) {
        int n = nBase + wn * 64 + j * 16 + ln;
        float bev = be[n];
        #pragma unroll
        for (int i = 0; i < 4; ++i) {
            #pragma unroll
            for (int r = 0; r < 4; ++r) {
                int m = mBase + wm * 64 + i * 16 + quad * 4 + r;
                out[(size_t)m * N + n] = fmaxf(acc[i][j][r] + bev, 0.f);
            }
        }
    }
#undef STAGE_B
#undef STAGE_A
}

// ---------------------------------------------------------------------------
// R3 fallback GEMM (on-the-fly A split) — only if ws/shape precludes fast path.
// ---------------------------------------------------------------------------
__global__ __launch_bounds__(256)
void gemm_split_bf16(const float* __restrict__ x, const float* __restrict__ pb,
                     const unsigned short* __restrict__ Wt_hi,
                     const unsigned short* __restrict__ Wt_lo,
                     const float* __restrict__ be,
                     float* __restrict__ out, int M, int N, int Kdim) {
    __shared__ unsigned short sAhi[128][32];
    __shared__ unsigned short sAlo[128][32];
    __shared__ unsigned short sBhi[128][32];
    __shared__ unsigned short sBlo[128][32];

    const int tx    = threadIdx.x;
    const int nBase = blockIdx.x * 128;
    const int mBase = blockIdx.y * 128;
    const int wv    = tx >> 6;
    const int lane  = tx & 63;
    const int ln    = lane & 15;
    const int quad  = lane >> 4;
    const int wm    = wv >> 1;
    const int wn    = wv & 1;
    const int am = tx >> 1;
    const int ak = (tx & 1) * 16;
    const int bn  = wv * 16 + (lane >> 2);
    const int bk8 = (lane & 3) * 8;

    f32x4 acc[4][4] = {};

    for (int k0 = 0; k0 < Kdim; k0 += 32) {
        __syncthreads();
        #pragma unroll
        for (int r = 0; r < 2; ++r) {
            int nrow = r * 64 + bn;
            size_t goff = (size_t)(nBase + nrow) * Kdim + k0 + bk8;
            GLL16(&Wt_hi[goff], &sBhi[nrow][bk8]);
            GLL16(&Wt_lo[goff], &sBlo[nrow][bk8]);
        }
        {
            const float* xrow = x  + (size_t)(mBase + am) * Kdim + k0 + ak;
            const float* pbp  = pb + k0 + ak;
            float v[16];
            #pragma unroll
            for (int q = 0; q < 4; ++q) {
                float4 xv = *(const float4*)(xrow + q * 4);
                float4 pv = *(const float4*)(pbp + q * 4);
                v[q*4+0] = xv.x - pv.x; v[q*4+1] = xv.y - pv.y;
                v[q*4+2] = xv.z - pv.z; v[q*4+3] = xv.w - pv.w;
            }
            __align__(16) unsigned short hi[16], lo[16];
            #pragma unroll
            for (int q = 0; q < 16; ++q) {
                hi[q] = f2bf(v[q]);
                lo[q] = f2bf(v[q] - bf2f(hi[q]));
            }
            *(uint4*)&sAhi[am][ak]     = *(uint4*)&hi[0];
            *(uint4*)&sAhi[am][ak + 8] = *(uint4*)&hi[8];
            *(uint4*)&sAlo[am][ak]     = *(uint4*)&lo[0];
            *(uint4*)&sAlo[am][ak + 8] = *(uint4*)&lo[8];
        }
        __syncthreads();

        bf16x8 ahi[4], alo[4], bhi[4], blo[4];
        #pragma unroll
        for (int i = 0; i < 4; ++i) {
            int m = wm * 64 + i * 16 + ln;
            ahi[i] = *(const bf16x8*)&sAhi[m][quad * 8];
            alo[i] = *(const bf16x8*)&sAlo[m][quad * 8];
        }
        #pragma unroll
        for (int j = 0; j < 4; ++j) {
            int n = wn * 64 + j * 16 + ln;
            bhi[j] = *(const bf16x8*)&sBhi[n][quad * 8];
            blo[j] = *(const bf16x8*)&sBlo[n][quad * 8];
        }
        #pragma unroll
        for (int i = 0; i < 4; ++i)
            #pragma unroll
            for (int j = 0; j < 4; ++j) {
                acc[i][j] = __builtin_amdgcn_mfma_f32_16x16x32_bf16(ahi[i], bhi[j], acc[i][j], 0, 0, 0);
                acc[i][j] = __builtin_amdgcn_mfma_f32_16x16x32_bf16(ahi[i], blo[j], acc[i][j], 0, 0, 0);
                acc[i][j] = __builtin_amdgcn_mfma_f32_16x16x32_bf16(alo[i], bhi[j], acc[i][j], 0, 0, 0);
            }
    }

    #pragma unroll
    for (int j = 0; j < 4; ++j) {
        int n = nBase + wn * 64 + j * 16 + ln;
        float bev = be[n];
        #pragma unroll
        for (int i = 0; i < 4; ++i)
            #pragma unroll
            for (int r = 0; r < 4; ++r) {
                int m = mBase + wm * 64 + i * 16 + quad * 4 + r;
                out[(size_t)m * N + n] = fmaxf(acc[i][j][r] + bev, 0.f);
            }
    }
}

// ---------------------------------------------------------------------------
// Top-k mask. Threshold by register-resident bit-bisection (exact: positive
// float order == uint order), then the proven R2 f64 band machinery.
// ---------------------------------------------------------------------------
#define BAND    2e-4f
#define AMB_CAP 64

__global__ __launch_bounds__(256)
void topk_mask_exact(const float* __restrict__ x, const float* __restrict__ pb,
                     const float* __restrict__ W, const float* __restrict__ be,
                     float* __restrict__ out, int N, int Kdim, int Ksel) {
    __shared__ int    s_red[4];
    __shared__ int    s_nhi, s_namb;
    __shared__ int    amb_idx[AMB_CAP];
    __shared__ double amb_d[AMB_CAP];
    __shared__ int    amb_keep[AMB_CAP];
    __shared__ double dred[4];

    const int tx  = threadIdx.x;
    const int row = blockIdx.x;
    float* rowp = out + (size_t)row * N;

    float v[16];
    #pragma unroll
    for (int p = 0; p < 4; ++p) {
        float4 f = *(const float4*)&rowp[(tx + 256 * p) << 2];
        v[p*4+0] = f.x; v[p*4+1] = f.y; v[p*4+2] = f.z; v[p*4+3] = f.w;
    }
    unsigned uv[16];
    #pragma unroll
    for (int i = 0; i < 16; ++i) uv[i] = __float_as_uint(v[i]);

    int c0 = 0;
    #pragma unroll
    for (int i = 0; i < 16; ++i) c0 += (uv[i] != 0u) ? 1 : 0;
    #pragma unroll
    for (int off = 32; off > 0; off >>= 1) c0 += __shfl_down(c0, off);
    if ((tx & 63) == 0) s_red[tx >> 6] = c0;
    __syncthreads();
    const int total_nz = s_red[0] + s_red[1] + s_red[2] + s_red[3];

    unsigned thr_u = 0;
    if (total_nz >= Ksel) {
        unsigned blo_ = 1u, bhi_ = 0x7f7fffffu;
        while (blo_ < bhi_) {
            unsigned mid = blo_ + ((bhi_ - blo_ + 1) >> 1);
            int cc = 0;
            #pragma unroll
            for (int i = 0; i < 16; ++i) cc += (uv[i] >= mid) ? 1 : 0;
            #pragma unroll
            for (int off = 32; off > 0; off >>= 1) cc += __shfl_down(cc, off);
            __syncthreads();
            if ((tx & 63) == 0) s_red[tx >> 6] = cc;
            __syncthreads();
            int cnt = s_red[0] + s_red[1] + s_red[2] + s_red[3];
            if (cnt >= Ksel) blo_ = mid; else bhi_ = mid - 1;
        }
        thr_u = blo_;
    }
    const float thr = __uint_as_float(thr_u);

    if (thr < 0.01f) {
        #pragma unroll
        for (int p = 0; p < 4; ++p) {
            float4 o;
            o.x = (v[p*4+0] >= thr) ? v[p*4+0] : 0.f;
            o.y = (v[p*4+1] >= thr) ? v[p*4+1] : 0.f;
            o.z = (v[p*4+2] >= thr) ? v[p*4+2] : 0.f;
            o.w = (v[p*4+3] >= thr) ? v[p*4+3] : 0.f;
            *(float4*)&rowp[(tx + 256 * p) << 2] = o;
        }
        return;
    }

    if (tx == 0) { s_nhi = 0; s_namb = 0; }
    __syncthreads();

    int my_hi = 0;
    #pragma unroll
    for (int i = 0; i < 16; ++i) {
        float val = v[i];
        if (val > thr + BAND) my_hi++;
        else if (val >= thr - BAND) {
            int slot = atomicAdd(&s_namb, 1);
            if (slot < AMB_CAP) amb_idx[slot] = ((tx + 256 * (i >> 2)) << 2) + (i & 3);
        }
    }
    atomicAdd(&s_nhi, my_hi);
    __syncthreads();

    const int nhi   = s_nhi;
    const int namb  = (s_namb < AMB_CAP) ? s_namb : AMB_CAP;
    const int kneed = Ksel - nhi;
    const bool fallback = (s_namb > AMB_CAP) || (kneed < 0) || (kneed > s_namb);

    if (fallback) {
        #pragma unroll
        for (int p = 0; p < 4; ++p) {
            float4 o;
            o.x = (v[p*4+0] >= thr) ? v[p*4+0] : 0.f;
            o.y = (v[p*4+1] >= thr) ? v[p*4+1] : 0.f;
            o.z = (v[p*4+2] >= thr) ? v[p*4+2] : 0.f;
            o.w = (v[p*4+3] >= thr) ? v[p*4+3] : 0.f;
            *(float4*)&rowp[(tx + 256 * p) << 2] = o;
        }
        return;
    }

    if (namb > kneed) {
        for (int j = 0; j < namb; ++j) {
            const int n = amb_idx[j];
            double partial = 0.0;
            for (int p = 0; p < Kdim / 256; ++p) {
                int k = tx + 256 * p;
                partial += ((double)x[(size_t)row * Kdim + k] - (double)pb[k]) *
                           (double)W[(size_t)k * N + n];
            }
            #pragma unroll
            for (int off = 32; off > 0; off >>= 1) partial += __shfl_down(partial, off);
            if ((tx & 63) == 0) dred[tx >> 6] = partial;
            __syncthreads();
            if (tx == 0) amb_d[j] = dred[0] + dred[1] + dred[2] + dred[3] + (double)be[n];
            __syncthreads();
        }
        if (tx == 0) {
            for (int j = 0; j < namb; ++j) {
                int greater = 0;
                for (int l = 0; l < namb; ++l)
                    if (amb_d[l] > amb_d[j]) greater++;
                amb_keep[j] = (greater < kneed) ? 1 : 0;
            }
        }
        __syncthreads();
    } else {
        for (int j = tx; j < namb; j += 256) amb_keep[j] = 1;
        __syncthreads();
    }

    #pragma unroll
    for (int p = 0; p < 4; ++p) {
        float4 o;
        float* po = (float*)&o;
        #pragma unroll
        for (int r = 0; r < 4; ++r) {
            int gi = ((tx + 256 * p) << 2) + r;
            float val = v[p*4+r];
            float ov;
            if (val > thr + BAND) ov = val;
            else if (val < thr - BAND) ov = 0.f;
            else {
                int keep = 0;
                for (int j = 0; j < namb; ++j)
                    if (amb_idx[j] == gi) { keep = amb_keep[j]; break; }
                ov = keep ? val : 0.f;
            }
            po[r] = ov;
        }
        *(float4*)&rowp[(tx + 256 * p) << 2] = o;
    }
}

extern "C" void kernel_launch(void* const* d_in, const int* in_sizes, int n_in,
                              void* d_out, int out_size, void* d_ws, size_t ws_size,
                              hipStream_t stream) {
    const float* x  = (const float*)d_in[0];
    const float* pb = (const float*)d_in[1];
    const float* W  = (const float*)d_in[2];
    const float* be = (const float*)d_in[3];
    float* out = (float*)d_out;

    const int D = in_sizes[1];          // 4096
    const int N = in_sizes[3];          // 4096
    const int M = in_sizes[0] / D;      // 16384

    const size_t szW = (size_t)N * D;   // elements per W plane
    const size_t szX = (size_t)M * D;   // elements per X plane
    const size_t needW    = 2ull * szW * sizeof(unsigned short);            // 64 MB
    const size_t needFull = needW + 2ull * szX * sizeof(unsigned short);    // 332 MB

    const bool divOK = (M % 128 == 0) && (N % 128 == 0) && (D % 2048 == 0);

    if (ws_size >= needFull && divOK) {
        unsigned short* Wt_hi = (unsigned short*)d_ws;
        unsigned short* Wt_lo = Wt_hi + szW;
        unsigned short* Xhi   = Wt_lo + szW;
        unsigned short* Xlo   = Xhi + szX;
        split_transpose_W<<<dim3(N / 64, D / 64), 256, 0, stream>>>(W, Wt_hi, Wt_lo, N, D);
        presplit_x<<<M, 256, 0, stream>>>(x, pb, Xhi, Xlo, D);
        gemm_presplit_2b<<<dim3(N / 128, M / 128), 256, 0, stream>>>(
            Xhi, Xlo, Wt_hi, Wt_lo, be, out, M, N, D);
    } else {
        unsigned short* Wt_hi = (unsigned short*)d_ws;
        unsigned short* Wt_lo = Wt_hi + szW;
        split_transpose_W<<<dim3(N / 64, D / 64), 256, 0, stream>>>(W, Wt_hi, Wt_lo, N, D);
        gemm_split_bf16<<<dim3(N / 128, M / 128), 256, 0, stream>>>(
            x, pb, Wt_hi, Wt_lo, be, out, M, N, D);
    }
    topk_mask_exact<<<M, 256, 0, stream>>>(x, pb, W, be, out, N, D, 128);
}

// Round 6
// 2138.145 us; speedup vs baseline: 1.2108x; 1.2108x over previous
//
#include <hip/hip_runtime.h>
#include <hip/hip_bf16.h>

// ---------------------------------------------------------------------------
// y = relu((x - pb) @ W + be); thr = 128th largest per row; out = y*(y>=thr).
// M=16384, K=4096, N=4096, fp32 in/out.
//
// R9: revert to the R7 GEMM structure (256^2 tile, 8 waves, 4 phases/K-tile,
// 4-plane interleaved 128B LDS rows + 3-bit XOR swizzle, counted vmcnt
// {4,5,6,3}, setprio, n-major XCD swizzle) — R8's 2-block experiment was
// refuted (same 8 waves/CU, doubled FETCH, MfmaUtil 36%). ONE change:
// MFMA shape 16x16x32 -> 32x32x16 (pipe ceiling 2382-2495 vs 2075 TF,
// m06/m119; half the MFMA instruction count). Fragment rows are 32-aligned
// so the proven swizzle keeps 2-way (free) LDS access. Top-k: R7 bisection.
// ---------------------------------------------------------------------------

typedef __bf16  bf16x8 __attribute__((ext_vector_type(8)));
typedef float   f32x4  __attribute__((ext_vector_type(4)));
typedef float   f32x16 __attribute__((ext_vector_type(16)));

__device__ __forceinline__ unsigned short f2bf(float f) {
    __hip_bfloat16 h = __float2bfloat16(f);
    return __builtin_bit_cast(unsigned short, h);
}
__device__ __forceinline__ float bf2f(unsigned short u) {
    __hip_bfloat16 h = __builtin_bit_cast(__hip_bfloat16, u);
    return __bfloat162float(h);
}

#define GLL16(g, l)                                                          \
    __builtin_amdgcn_global_load_lds(                                        \
        (const __attribute__((address_space(1))) unsigned int*)(g),          \
        (__attribute__((address_space(3))) unsigned int*)(l), 16, 0, 0)

// ---------------------------------------------------------------------------
// x [m][k] fp32 -> Xhi/Xlo [m][k] bf16 (pb folded in). One row per block.
// ---------------------------------------------------------------------------
__global__ __launch_bounds__(256)
void presplit_x(const float* __restrict__ x, const float* __restrict__ pb,
                unsigned short* __restrict__ Xhi, unsigned short* __restrict__ Xlo,
                int Kdim) {
    const size_t rbase = (size_t)blockIdx.x * Kdim;
    for (int it = 0; it < Kdim; it += 2048) {
        const int k8 = it + threadIdx.x * 8;
        __align__(16) unsigned short hi[8], lo[8];
        #pragma unroll
        for (int q = 0; q < 2; ++q) {
            float4 xv = *(const float4*)&x[rbase + k8 + q * 4];
            float4 pv = *(const float4*)&pb[k8 + q * 4];
            float v[4] = {xv.x - pv.x, xv.y - pv.y, xv.z - pv.z, xv.w - pv.w};
            #pragma unroll
            for (int r = 0; r < 4; ++r) {
                hi[q*4+r] = f2bf(v[r]);
                lo[q*4+r] = f2bf(v[r] - bf2f(hi[q*4+r]));
            }
        }
        *(uint4*)&Xhi[rbase + k8] = *(uint4*)&hi[0];
        *(uint4*)&Xlo[rbase + k8] = *(uint4*)&lo[0];
    }
}

// ---------------------------------------------------------------------------
// W [k][n] fp32 -> Wt_hi/Wt_lo [n][k] bf16 (transpose + split).
// ---------------------------------------------------------------------------
__global__ __launch_bounds__(256)
void split_transpose_W(const float* __restrict__ W,
                       unsigned short* __restrict__ Wt_hi,
                       unsigned short* __restrict__ Wt_lo,
                       int N, int Kdim) {
    __shared__ float tile[64][65];
    const int tx = threadIdx.x;
    const int nB = blockIdx.x * 64;
    const int kB = blockIdx.y * 64;

    #pragma unroll
    for (int p = 0; p < 4; ++p) {
        int e  = tx + 256 * p;
        int kl = e >> 4;
        int n4 = (e & 15) << 2;
        float4 v = *(const float4*)&W[(size_t)(kB + kl) * N + nB + n4];
        tile[kl][n4 + 0] = v.x; tile[kl][n4 + 1] = v.y;
        tile[kl][n4 + 2] = v.z; tile[kl][n4 + 3] = v.w;
    }
    __syncthreads();

    #pragma unroll
    for (int p = 0; p < 4; ++p) {
        int e  = tx + 256 * p;
        int nl = e >> 4;
        int k4 = (e & 15) << 2;
        unsigned short hi[4], lo[4];
        #pragma unroll
        for (int r = 0; r < 4; ++r) {
            float f = tile[k4 + r][nl];
            hi[r] = f2bf(f);
            lo[r] = f2bf(f - bf2f(hi[r]));
        }
        size_t off = (size_t)(nB + nl) * Kdim + kB + k4;
        *(ushort4*)&Wt_hi[off] = *(ushort4*)&hi[0];
        *(ushort4*)&Wt_lo[off] = *(ushort4*)&lo[0];
    }
}

// ---------------------------------------------------------------------------
// 256x256 tile, BK=32, 8 waves (2Mx4N), 32x32x16 MFMA.
// LDS rows 128B = [hi c0..3 | lo c0..3], phys chunk = logical ^ (row&7).
// Wave owns 128x64 = 4 mtiles x 2 ntiles of 32x32, acc f32x16[4][2].
// Phase q (q=0..3): A frags of mtile q (4 ds_read_b128) + 12 MFMA.
// B frags (8 b128) read once at phase 0. Staging/vmcnt identical to R7:
// per tile issue B0 B1 | B2 B3 | A0 A1 | A2 A3, waits {4,5,6,3}.
// ---------------------------------------------------------------------------
__global__ __launch_bounds__(512, 2)
void gemm_presplit_32(const unsigned short* __restrict__ Xhi,
                      const unsigned short* __restrict__ Xlo,
                      const unsigned short* __restrict__ Wt_hi,
                      const unsigned short* __restrict__ Wt_lo,
                      const float* __restrict__ be,
                      float* __restrict__ out, int M, int N, int Kdim) {
    __shared__ unsigned short sA[2][256 * 64];   // 256 rows x 128B
    __shared__ unsigned short sB[2][256 * 64];

    const int tx   = threadIdx.x;
    const int lane = tx & 63;
    const int wv   = tx >> 6;          // 0..7
    const int l31  = lane & 31;
    const int lh   = lane >> 5;        // k-group half (0..1)
    const int sw7  = lane & 7;         // == (frag row)&7 for 32-aligned rows
    const int wm   = wv >> 2;          // 0..1 (M half)
    const int wn   = wv & 3;           // 0..3 (N quarter)

    // n-major bijective XCD swizzle: one A-panel per XCD stays L2-resident.
    const int mT = M >> 8, nT = N >> 8, total = mT * nT;
    int wgid = blockIdx.y * gridDim.x + blockIdx.x;
    int xcd = wgid & 7, idx = wgid >> 3;
    int qq = total >> 3, rr_ = total & 7;
    int swz = (xcd < rr_ ? xcd * (qq + 1) : rr_ * (qq + 1) + (xcd - rr_) * qq) + idx;
    const int mBase = (swz / nT) << 8;
    const int nBase = (swz % nT) << 8;

    // staging: 512 thr x 16B = 8KB round = 64 rows x 128B (identical to R7)
    const int rr  = tx >> 3;           // 0..63 row-within-round
    const int lc8 = tx & 7;            // dest (physical) 16B chunk, linear
    const int lgc = lc8 ^ (rr & 7);    // logical chunk held at this dest slot
    const unsigned short* aSrc = (lgc & 4) ? Xlo : Xhi;
    const unsigned short* bSrc = (lgc & 4) ? Wt_lo : Wt_hi;
    const int srcoff = (lgc & 3) << 3;            // element offset within k-tile
    const int arow_b = (rr & 31) + ((rr & 32) << 2);  // + (r<<5): both wm halves

#define STAGE_B(bufp, r, k0_) do {                                            \
        int row_ = ((r) << 6) + rr;                                           \
        GLL16(bSrc + (size_t)(nBase + row_) * Kdim + (k0_) + srcoff,          \
              &sB[bufp][(row_ << 6) + (lc8 << 3)]);                           \
    } while (0)
#define STAGE_A(bufp, r, k0_) do {                                            \
        int row_ = ((r) << 5) + arow_b;                                       \
        GLL16(aSrc + (size_t)(mBase + row_) * Kdim + (k0_) + srcoff,          \
              &sA[bufp][(row_ << 6) + (lc8 << 3)]);                           \
    } while (0)
    // fragment read (32x32x16): operand dim = lane&31, kgroup = lane>>5.
    // hi plane, kslot ks: logical chunk = 2*ks + lh; lo plane: +4.
    // phys = logical ^ (row&7) = logical ^ sw7 (rows 32-aligned).
#define FRAG(buf, row0, slot) \
    (*(const bf16x8*)&(buf)[(((row0) + l31) << 6) + (((slot) ^ sw7) << 3)])

    f32x16 acc[4][2] = {};

    const int NT = Kdim >> 5;          // K-tiles (BK=32)

    // prologue: stage tile 0 fully into buf 0 (order B0..B3, A0..A3)
    STAGE_B(0, 0, 0); STAGE_B(0, 1, 0); STAGE_B(0, 2, 0); STAGE_B(0, 3, 0);
    STAGE_A(0, 0, 0); STAGE_A(0, 1, 0); STAGE_A(0, 2, 0); STAGE_A(0, 3, 0);
    asm volatile("s_waitcnt vmcnt(0)" ::: "memory");
    __builtin_amdgcn_s_barrier();
    __builtin_amdgcn_sched_barrier(0);

    for (int t = 0; t < NT; ++t) {
        const int cur = t & 1, nxt = cur ^ 1;
        const bool more = (t + 1 < NT);
        const int k1 = (t + 1) << 5;

        bf16x8 bh[2][2], bl[2][2];     // [ntile][kslot], read at ph0, held
        #pragma unroll
        for (int q = 0; q < 4; ++q) {
            if (q == 0) {
                #pragma unroll
                for (int nt = 0; nt < 2; ++nt) {
                    int rb0 = wn * 64 + nt * 32;
                    #pragma unroll
                    for (int ks = 0; ks < 2; ++ks) {
                        bh[nt][ks] = FRAG(sB[cur], rb0, 2 * ks + lh);
                        bl[nt][ks] = FRAG(sB[cur], rb0, 2 * ks + lh + 4);
                    }
                }
            }
            bf16x8 ah[2], al[2];       // mtile q, [kslot]
            {
                int ra0 = wm * 128 + q * 32;
                #pragma unroll
                for (int ks = 0; ks < 2; ++ks) {
                    ah[ks] = FRAG(sA[cur], ra0, 2 * ks + lh);
                    al[ks] = FRAG(sA[cur], ra0, 2 * ks + lh + 4);
                }
            }

            if (more) {                  // 2 staging rounds for tile t+1
                if (q == 0)      { STAGE_B(nxt, 0, k1); STAGE_B(nxt, 1, k1); }
                else if (q == 1) { STAGE_B(nxt, 2, k1); STAGE_B(nxt, 3, k1); }
                else if (q == 2) { STAGE_A(nxt, 0, k1); STAGE_A(nxt, 1, k1); }
                else             { STAGE_A(nxt, 2, k1); STAGE_A(nxt, 3, k1); }
            }

            __builtin_amdgcn_s_barrier();
            __builtin_amdgcn_s_setprio(1);
            // 12 MFMA (32x32x16): product-outer, acc dep distance 2 issues
            #pragma unroll
            for (int ks = 0; ks < 2; ++ks)
                #pragma unroll
                for (int nt = 0; nt < 2; ++nt)
                    acc[q][nt] = __builtin_amdgcn_mfma_f32_32x32x16_bf16(
                        ah[ks], bh[nt][ks], acc[q][nt], 0, 0, 0);
            #pragma unroll
            for (int ks = 0; ks < 2; ++ks)
                #pragma unroll
                for (int nt = 0; nt < 2; ++nt)
                    acc[q][nt] = __builtin_amdgcn_mfma_f32_32x32x16_bf16(
                        ah[ks], bl[nt][ks], acc[q][nt], 0, 0, 0);
            #pragma unroll
            for (int ks = 0; ks < 2; ++ks)
                #pragma unroll
                for (int nt = 0; nt < 2; ++nt)
                    acc[q][nt] = __builtin_amdgcn_mfma_f32_32x32x16_bf16(
                        al[ks], bh[nt][ks], acc[q][nt], 0, 0, 0);
            __builtin_amdgcn_s_setprio(0);

            // counted waits (identical ledger to R7)
            if (more) {
                if (q == 0)      asm volatile("s_waitcnt vmcnt(4)" ::: "memory");
                else if (q == 1) asm volatile("s_waitcnt vmcnt(5)" ::: "memory");
                else if (q == 2) asm volatile("s_waitcnt vmcnt(6)" ::: "memory");
                else             asm volatile("s_waitcnt vmcnt(3)" ::: "memory");
            } else {
                if (q == 0)      asm volatile("s_waitcnt vmcnt(2)" ::: "memory");
                else if (q == 1) asm volatile("s_waitcnt vmcnt(1)" ::: "memory");
                else if (q == 2) asm volatile("s_waitcnt vmcnt(0)" ::: "memory");
            }
            __builtin_amdgcn_s_barrier();
            __builtin_amdgcn_sched_barrier(0);
        }
    }

    // epilogue (32x32 C/D: col=lane&31, row=(r&3)+8*(r>>2)+4*(lane>>5))
    #pragma unroll
    for (int nt = 0; nt < 2; ++nt) {
        int n = nBase + wn * 64 + nt * 32 + l31;
        float bev = be[n];
        #pragma unroll
        for (int mt = 0; mt < 4; ++mt) {
            #pragma unroll
            for (int r = 0; r < 16; ++r) {
                int row = (r & 3) + 8 * (r >> 2) + 4 * lh;
                int m = mBase + wm * 128 + mt * 32 + row;
                out[(size_t)m * N + n] = fmaxf(acc[mt][nt][r] + bev, 0.f);
            }
        }
    }
#undef STAGE_B
#undef STAGE_A
#undef FRAG
}

// ---------------------------------------------------------------------------
// R3 fallback GEMM (on-the-fly A split) — only if ws/shape precludes fast path.
// ---------------------------------------------------------------------------
__global__ __launch_bounds__(256)
void gemm_split_bf16(const float* __restrict__ x, const float* __restrict__ pb,
                     const unsigned short* __restrict__ Wt_hi,
                     const unsigned short* __restrict__ Wt_lo,
                     const float* __restrict__ be,
                     float* __restrict__ out, int M, int N, int Kdim) {
    __shared__ unsigned short sAhi[128][32];
    __shared__ unsigned short sAlo[128][32];
    __shared__ unsigned short sBhi[128][32];
    __shared__ unsigned short sBlo[128][32];

    const int tx    = threadIdx.x;
    const int nBase = blockIdx.x * 128;
    const int mBase = blockIdx.y * 128;
    const int wv    = tx >> 6;
    const int lane  = tx & 63;
    const int ln    = lane & 15;
    const int quad  = lane >> 4;
    const int wm    = wv >> 1;
    const int wn    = wv & 1;
    const int am = tx >> 1;
    const int ak = (tx & 1) * 16;
    const int bn  = wv * 16 + (lane >> 2);
    const int bk8 = (lane & 3) * 8;

    f32x4 acc[4][4] = {};

    for (int k0 = 0; k0 < Kdim; k0 += 32) {
        __syncthreads();
        #pragma unroll
        for (int r = 0; r < 2; ++r) {
            int nrow = r * 64 + bn;
            size_t goff = (size_t)(nBase + nrow) * Kdim + k0 + bk8;
            GLL16(&Wt_hi[goff], &sBhi[nrow][bk8]);
            GLL16(&Wt_lo[goff], &sBlo[nrow][bk8]);
        }
        {
            const float* xrow = x  + (size_t)(mBase + am) * Kdim + k0 + ak;
            const float* pbp  = pb + k0 + ak;
            float v[16];
            #pragma unroll
            for (int q = 0; q < 4; ++q) {
                float4 xv = *(const float4*)(xrow + q * 4);
                float4 pv = *(const float4*)(pbp + q * 4);
                v[q*4+0] = xv.x - pv.x; v[q*4+1] = xv.y - pv.y;
                v[q*4+2] = xv.z - pv.z; v[q*4+3] = xv.w - pv.w;
            }
            __align__(16) unsigned short hi[16], lo[16];
            #pragma unroll
            for (int q = 0; q < 16; ++q) {
                hi[q] = f2bf(v[q]);
                lo[q] = f2bf(v[q] - bf2f(hi[q]));
            }
            *(uint4*)&sAhi[am][ak]     = *(uint4*)&hi[0];
            *(uint4*)&sAhi[am][ak + 8] = *(uint4*)&hi[8];
            *(uint4*)&sAlo[am][ak]     = *(uint4*)&lo[0];
            *(uint4*)&sAlo[am][ak + 8] = *(uint4*)&lo[8];
        }
        __syncthreads();

        bf16x8 ahi[4], alo[4], bhi[4], blo[4];
        #pragma unroll
        for (int i = 0; i < 4; ++i) {
            int m = wm * 64 + i * 16 + ln;
            ahi[i] = *(const bf16x8*)&sAhi[m][quad * 8];
            alo[i] = *(const bf16x8*)&sAlo[m][quad * 8];
        }
        #pragma unroll
        for (int j = 0; j < 4; ++j) {
            int n = wn * 64 + j * 16 + ln;
            bhi[j] = *(const bf16x8*)&sBhi[n][quad * 8];
            blo[j] = *(const bf16x8*)&sBlo[n][quad * 8];
        }
        #pragma unroll
        for (int i = 0; i < 4; ++i)
            #pragma unroll
            for (int j = 0; j < 4; ++j) {
                acc[i][j] = __builtin_amdgcn_mfma_f32_16x16x32_bf16(ahi[i], bhi[j], acc[i][j], 0, 0, 0);
                acc[i][j] = __builtin_amdgcn_mfma_f32_16x16x32_bf16(ahi[i], blo[j], acc[i][j], 0, 0, 0);
                acc[i][j] = __builtin_amdgcn_mfma_f32_16x16x32_bf16(alo[i], bhi[j], acc[i][j], 0, 0, 0);
            }
    }

    #pragma unroll
    for (int j = 0; j < 4; ++j) {
        int n = nBase + wn * 64 + j * 16 + ln;
        float bev = be[n];
        #pragma unroll
        for (int i = 0; i < 4; ++i)
            #pragma unroll
            for (int r = 0; r < 4; ++r) {
                int m = mBase + wm * 64 + i * 16 + quad * 4 + r;
                out[(size_t)m * N + n] = fmaxf(acc[i][j][r] + bev, 0.f);
            }
    }
}

// ---------------------------------------------------------------------------
// Top-k mask. Threshold by register-resident bit-bisection (exact: positive
// float order == uint order), then the proven R2 f64 band machinery.
// ---------------------------------------------------------------------------
#define BAND    2e-4f
#define AMB_CAP 64

__global__ __launch_bounds__(256)
void topk_mask_exact(const float* __restrict__ x, const float* __restrict__ pb,
                     const float* __restrict__ W, const float* __restrict__ be,
                     float* __restrict__ out, int N, int Kdim, int Ksel) {
    __shared__ int    s_red[4];
    __shared__ int    s_nhi, s_namb;
    __shared__ int    amb_idx[AMB_CAP];
    __shared__ double amb_d[AMB_CAP];
    __shared__ int    amb_keep[AMB_CAP];
    __shared__ double dred[4];

    const int tx  = threadIdx.x;
    const int row = blockIdx.x;
    float* rowp = out + (size_t)row * N;

    float v[16];
    #pragma unroll
    for (int p = 0; p < 4; ++p) {
        float4 f = *(const float4*)&rowp[(tx + 256 * p) << 2];
        v[p*4+0] = f.x; v[p*4+1] = f.y; v[p*4+2] = f.z; v[p*4+3] = f.w;
    }
    unsigned uv[16];
    #pragma unroll
    for (int i = 0; i < 16; ++i) uv[i] = __float_as_uint(v[i]);

    int c0 = 0;
    #pragma unroll
    for (int i = 0; i < 16; ++i) c0 += (uv[i] != 0u) ? 1 : 0;
    #pragma unroll
    for (int off = 32; off > 0; off >>= 1) c0 += __shfl_down(c0, off);
    if ((tx & 63) == 0) s_red[tx >> 6] = c0;
    __syncthreads();
    const int total_nz = s_red[0] + s_red[1] + s_red[2] + s_red[3];

    unsigned thr_u = 0;
    if (total_nz >= Ksel) {
        unsigned blo_ = 1u, bhi_ = 0x7f7fffffu;
        while (blo_ < bhi_) {
            unsigned mid = blo_ + ((bhi_ - blo_ + 1) >> 1);
            int cc = 0;
            #pragma unroll
            for (int i = 0; i < 16; ++i) cc += (uv[i] >= mid) ? 1 : 0;
            #pragma unroll
            for (int off = 32; off > 0; off >>= 1) cc += __shfl_down(cc, off);
            __syncthreads();
            if ((tx & 63) == 0) s_red[tx >> 6] = cc;
            __syncthreads();
            int cnt = s_red[0] + s_red[1] + s_red[2] + s_red[3];
            if (cnt >= Ksel) blo_ = mid; else bhi_ = mid - 1;
        }
        thr_u = blo_;
    }
    const float thr = __uint_as_float(thr_u);

    if (thr < 0.01f) {
        #pragma unroll
        for (int p = 0; p < 4; ++p) {
            float4 o;
            o.x = (v[p*4+0] >= thr) ? v[p*4+0] : 0.f;
            o.y = (v[p*4+1] >= thr) ? v[p*4+1] : 0.f;
            o.z = (v[p*4+2] >= thr) ? v[p*4+2] : 0.f;
            o.w = (v[p*4+3] >= thr) ? v[p*4+3] : 0.f;
            *(float4*)&rowp[(tx + 256 * p) << 2] = o;
        }
        return;
    }

    if (tx == 0) { s_nhi = 0; s_namb = 0; }
    __syncthreads();

    int my_hi = 0;
    #pragma unroll
    for (int i = 0; i < 16; ++i) {
        float val = v[i];
        if (val > thr + BAND) my_hi++;
        else if (val >= thr - BAND) {
            int slot = atomicAdd(&s_namb, 1);
            if (slot < AMB_CAP) amb_idx[slot] = ((tx + 256 * (i >> 2)) << 2) + (i & 3);
        }
    }
    atomicAdd(&s_nhi, my_hi);
    __syncthreads();

    const int nhi   = s_nhi;
    const int namb  = (s_namb < AMB_CAP) ? s_namb : AMB_CAP;
    const int kneed = Ksel - nhi;
    const bool fallback = (s_namb > AMB_CAP) || (kneed < 0) || (kneed > s_namb);

    if (fallback) {
        #pragma unroll
        for (int p = 0; p < 4; ++p) {
            float4 o;
            o.x = (v[p*4+0] >= thr) ? v[p*4+0] : 0.f;
            o.y = (v[p*4+1] >= thr) ? v[p*4+1] : 0.f;
            o.z = (v[p*4+2] >= thr) ? v[p*4+2] : 0.f;
            o.w = (v[p*4+3] >= thr) ? v[p*4+3] : 0.f;
            *(float4*)&rowp[(tx + 256 * p) << 2] = o;
        }
        return;
    }

    if (namb > kneed) {
        for (int j = 0; j < namb; ++j) {
            const int n = amb_idx[j];
            double partial = 0.0;
            for (int p = 0; p < Kdim / 256; ++p) {
                int k = tx + 256 * p;
                partial += ((double)x[(size_t)row * Kdim + k] - (double)pb[k]) *
                           (double)W[(size_t)k * N + n];
            }
            #pragma unroll
            for (int off = 32; off > 0; off >>= 1) partial += __shfl_down(partial, off);
            if ((tx & 63) == 0) dred[tx >> 6] = partial;
            __syncthreads();
            if (tx == 0) amb_d[j] = dred[0] + dred[1] + dred[2] + dred[3] + (double)be[n];
            __syncthreads();
        }
        if (tx == 0) {
            for (int j = 0; j < namb; ++j) {
                int greater = 0;
                for (int l = 0; l < namb; ++l)
                    if (amb_d[l] > amb_d[j]) greater++;
                amb_keep[j] = (greater < kneed) ? 1 : 0;
            }
        }
        __syncthreads();
    } else {
        for (int j = tx; j < namb; j += 256) amb_keep[j] = 1;
        __syncthreads();
    }

    #pragma unroll
    for (int p = 0; p < 4; ++p) {
        float4 o;
        float* po = (float*)&o;
        #pragma unroll
        for (int r = 0; r < 4; ++r) {
            int gi = ((tx + 256 * p) << 2) + r;
            float val = v[p*4+r];
            float ov;
            if (val > thr + BAND) ov = val;
            else if (val < thr - BAND) ov = 0.f;
            else {
                int keep = 0;
                for (int j = 0; j < namb; ++j)
                    if (amb_idx[j] == gi) { keep = amb_keep[j]; break; }
                ov = keep ? val : 0.f;
            }
            po[r] = ov;
        }
        *(float4*)&rowp[(tx + 256 * p) << 2] = o;
    }
}

extern "C" void kernel_launch(void* const* d_in, const int* in_sizes, int n_in,
                              void* d_out, int out_size, void* d_ws, size_t ws_size,
                              hipStream_t stream) {
    const float* x  = (const float*)d_in[0];
    const float* pb = (const float*)d_in[1];
    const float* W  = (const float*)d_in[2];
    const float* be = (const float*)d_in[3];
    float* out = (float*)d_out;

    const int D = in_sizes[1];          // 4096
    const int N = in_sizes[3];          // 4096
    const int M = in_sizes[0] / D;      // 16384

    const size_t szW = (size_t)N * D;   // elements per W plane
    const size_t szX = (size_t)M * D;   // elements per X plane
    const size_t needW    = 2ull * szW * sizeof(unsigned short);            // 64 MB
    const size_t needFull = needW + 2ull * szX * sizeof(unsigned short);    // 332 MB

    const bool divOK = (M % 256 == 0) && (N % 256 == 0) && (D % 2048 == 0);

    if (ws_size >= needFull && divOK) {
        unsigned short* Wt_hi = (unsigned short*)d_ws;
        unsigned short* Wt_lo = Wt_hi + szW;
        unsigned short* Xhi   = Wt_lo + szW;
        unsigned short* Xlo   = Xhi + szX;
        split_transpose_W<<<dim3(N / 64, D / 64), 256, 0, stream>>>(W, Wt_hi, Wt_lo, N, D);
        presplit_x<<<M, 256, 0, stream>>>(x, pb, Xhi, Xlo, D);
        gemm_presplit_32<<<dim3(N / 256, M / 256), 512, 0, stream>>>(
            Xhi, Xlo, Wt_hi, Wt_lo, be, out, M, N, D);
    } else {
        unsigned short* Wt_hi = (unsigned short*)d_ws;
        unsigned short* Wt_lo = Wt_hi + szW;
        split_transpose_W<<<dim3(N / 64, D / 64), 256, 0, stream>>>(W, Wt_hi, Wt_lo, N, D);
        gemm_split_bf16<<<dim3(N / 128, M / 128), 256, 0, stream>>>(
            x, pb, Wt_hi, Wt_lo, be, out, M, N, D);
    }
    topk_mask_exact<<<M, 256, 0, stream>>>(x, pb, W, be, out, N, D, 128);
}